// Round 1
// baseline (628.363 us; speedup 1.0000x reference)
//
#include <hip/hip_runtime.h>
#include <hip/hip_bf16.h>

typedef unsigned short u16;
typedef unsigned int u32;
typedef __attribute__((ext_vector_type(4))) float f32x4;
typedef __attribute__((ext_vector_type(8))) __bf16 bf16x8;

#define B_   2
#define T_   2048
#define DM   2048
#define NH   16
#define NKV  4
#define HD   128

__device__ __forceinline__ u16 f2bf(float f){
    u32 u = __builtin_bit_cast(u32, f);
    u += 0x7FFFu + ((u >> 16) & 1u);
    return (u16)(u >> 16);
}

__device__ __forceinline__ void gld_lds16(const void* g, void* l){
    __builtin_amdgcn_global_load_lds(
        (const __attribute__((address_space(1))) void*)g,
        (__attribute__((address_space(3))) void*)l, 16, 0, 0);
}

// ---------------- elementwise cast (f32 -> bf16), vectorized ----------------
__global__ void cast_v4(const float* __restrict__ in, u16* __restrict__ out){
    int i = blockIdx.x * 256 + threadIdx.x;
    float4 v = ((const float4*)in)[i];
    ushort4 o;
    o.x = f2bf(v.x); o.y = f2bf(v.y); o.z = f2bf(v.z); o.w = f2bf(v.w);
    ((ushort4*)out)[i] = o;
}

// ---------------- W (K,N) f32 -> Wt (N,K) bf16, tiled transpose ----------------
__global__ void transW(const float* __restrict__ W, u16* __restrict__ Wt, int K, int N){
    __shared__ float tile[32][33];
    int n0 = blockIdx.x * 32, k0 = blockIdx.y * 32;
    int tx = threadIdx.x, ty = threadIdx.y;
#pragma unroll
    for (int i = 0; i < 4; i++)
        tile[ty + i * 8][tx] = W[(size_t)(k0 + ty + i * 8) * N + n0 + tx];
    __syncthreads();
#pragma unroll
    for (int i = 0; i < 4; i++)
        Wt[(size_t)(n0 + ty + i * 8) * K + k0 + tx] = f2bf(tile[tx][ty + i * 8]);
}

// ---------------- RoPE + cast: q/k f32 (row-major (b*T+t, h*HD+d)) -> bf16 ----------------
__global__ void rope_cast(const float* __restrict__ in, u16* __restrict__ out, int HLOG){
    unsigned idx = blockIdx.x * 256 + threadIdx.x;
    int i = idx & 63;
    int h = (idx >> 6) & ((1u << HLOG) - 1);
    int t = (idx >> (6 + HLOG)) & 2047;
    int b = idx >> (17 + HLOG);
    size_t base = (size_t)((b << 11) | t) * (size_t)(128 << HLOG) + ((size_t)h << 7);
    float lo = in[base + i], hi = in[base + 64 + i];
    float ang = (float)t * exp2f((float)i * (-13.287712379549449f / 64.0f));
    float sv, cv;
    sincosf(ang, &sv, &cv);
    out[base + i]      = f2bf(lo * cv - hi * sv);
    out[base + 64 + i] = f2bf(hi * cv + lo * sv);
}

// ---------------- bf16 GEMM, C = A(M,K) * Bt(N,K)^T, m97 structure ----------------
template<typename OutT>
__global__ __launch_bounds__(256) void gemm_bt(const u16* __restrict__ A, const u16* __restrict__ Bt,
                                               OutT* __restrict__ C, int M, int N, int K){
    __shared__ __attribute__((aligned(16))) u16 As[128 * 32];
    __shared__ __attribute__((aligned(16))) u16 Bs[128 * 32];
    const int lane = threadIdx.x & 63;
    const int w = threadIdx.x >> 6;
    const int m0 = blockIdx.y * 128, n0 = blockIdx.x * 128;
    const int wr = w >> 1, wc = w & 1;
    const f32x4 Z = {0.f, 0.f, 0.f, 0.f};
    f32x4 acc[4][4];
#pragma unroll
    for (int i = 0; i < 4; i++)
#pragma unroll
        for (int j = 0; j < 4; j++) acc[i][j] = Z;
    const int rA = (lane >> 2);
    const int cA = (lane & 3) * 8;

    for (int k0 = 0; k0 < K; k0 += 32){
#pragma unroll
        for (int i = 0; i < 2; i++){
            int s = w + i * 4;
            gld_lds16(A  + (size_t)(m0 + s * 16 + rA) * K + k0 + cA, As + s * 512);
            gld_lds16(Bt + (size_t)(n0 + s * 16 + rA) * K + k0 + cA, Bs + s * 512);
        }
        __syncthreads();
        bf16x8 af[4], bfr[4];
#pragma unroll
        for (int mi = 0; mi < 4; mi++)
            af[mi] = *(const bf16x8*)(As + (wr * 64 + mi * 16 + (lane & 15)) * 32 + (lane >> 4) * 8);
#pragma unroll
        for (int ni = 0; ni < 4; ni++)
            bfr[ni] = *(const bf16x8*)(Bs + (wc * 64 + ni * 16 + (lane & 15)) * 32 + (lane >> 4) * 8);
#pragma unroll
        for (int mi = 0; mi < 4; mi++)
#pragma unroll
            for (int ni = 0; ni < 4; ni++)
                acc[mi][ni] = __builtin_amdgcn_mfma_f32_16x16x32_bf16(af[mi], bfr[ni], acc[mi][ni], 0, 0, 0);
        __syncthreads();
    }
#pragma unroll
    for (int mi = 0; mi < 4; mi++)
#pragma unroll
        for (int ni = 0; ni < 4; ni++)
#pragma unroll
            for (int j = 0; j < 4; j++){
                int r = m0 + wr * 64 + mi * 16 + (lane >> 4) * 4 + j;
                int c = n0 + wc * 64 + ni * 16 + (lane & 15);
                float v = acc[mi][ni][j];
                if constexpr (sizeof(OutT) == 2) C[(size_t)r * N + c] = (OutT)f2bf(v);
                else                             C[(size_t)r * N + c] = v;
            }
}

// ---------------- causal GQA flash attention ----------------
// Q: (b*T+t, h*HD+d) bf16; K/V: (b*T+s, hkv*HD+d) bf16; Y: (b*T+t, h*HD+d) bf16
__global__ __launch_bounds__(256) void attn(const u16* __restrict__ Q, const u16* __restrict__ Kb,
                                            const u16* __restrict__ Vb, u16* __restrict__ Y){
    __shared__ __attribute__((aligned(16))) u16 Ks[32 * 128];
    __shared__ __attribute__((aligned(16))) u16 Vt[128 * 32];
    __shared__ __attribute__((aligned(16))) u16 Pl[4][512];
    const int lane = threadIdx.x & 63, w = threadIdx.x >> 6;
    const int qt = blockIdx.x, h = blockIdx.y, b = blockIdx.z;
    const int hkv = h >> 2;
    const int q0 = qt * 64;
    const int qrow = q0 + w * 16 + (lane & 15);
    const f32x4 Z = {0.f, 0.f, 0.f, 0.f};

    bf16x8 qfr[4];
#pragma unroll
    for (int kk = 0; kk < 4; kk++)
        qfr[kk] = *(const bf16x8*)(Q + (size_t)(b * T_ + qrow) * DM + h * HD + kk * 32 + (lane >> 4) * 8);

    f32x4 accO[8];
#pragma unroll
    for (int i = 0; i < 8; i++) accO[i] = Z;
    float mr[4] = {-INFINITY, -INFINITY, -INFINITY, -INFINITY};
    float lr[4] = {0.f, 0.f, 0.f, 0.f};
    const int qend = q0 + w * 16 + 15;
    const int sEnd = q0 + 64;
    const float scale = 0.08838834764831845f;

    for (int s0 = 0; s0 < sEnd; s0 += 32){
        // ---- stage K (swizzled rows) and V^T ----
        {
            int r = threadIdx.x >> 3, cs = threadIdx.x & 7;
            const u16* kp = Kb + (size_t)(b * T_ + s0 + r) * (NKV * HD) + hkv * HD + cs * 16;
            uint4 ka = *(const uint4*)kp;
            uint4 kb2 = *(const uint4*)(kp + 8);
            u32 o0 = (u32)(r * 256 + cs * 32) ^ (u32)((r & 7) << 4);
            u32 o1 = (u32)(r * 256 + cs * 32 + 16) ^ (u32)((r & 7) << 4);
            *(uint4*)((char*)Ks + o0) = ka;
            *(uint4*)((char*)Ks + o1) = kb2;

            const u16* vp = Vb + (size_t)(b * T_ + s0 + r) * (NKV * HD) + hkv * HD + cs * 16;
            union { uint4 u; u16 s[8]; } v0, v1;
            v0.u = *(const uint4*)vp;
            v1.u = *(const uint4*)(vp + 8);
#pragma unroll
            for (int j = 0; j < 8; j++){
                int d0 = cs * 16 + j;
                u32 vo0 = (u32)(d0 * 64 + r * 2) ^ (u32)((d0 & 3) << 4);
                *(u16*)((char*)Vt + vo0) = v0.s[j];
                int d1 = cs * 16 + 8 + j;
                u32 vo1 = (u32)(d1 * 64 + r * 2) ^ (u32)((d1 & 3) << 4);
                *(u16*)((char*)Vt + vo1) = v1.s[j];
            }
        }
        __syncthreads();
        if (s0 <= qend){
            f32x4 sa[2];
            sa[0] = Z; sa[1] = Z;
#pragma unroll
            for (int c = 0; c < 2; c++){
                int kr = c * 16 + (lane & 15);
#pragma unroll
                for (int kk = 0; kk < 4; kk++){
                    u32 off = (u32)(kr * 256 + kk * 64 + (lane >> 4) * 16) ^ (u32)((kr & 7) << 4);
                    bf16x8 kf = *(const bf16x8*)((char*)Ks + off);
                    sa[c] = __builtin_amdgcn_mfma_f32_16x16x32_bf16(qfr[kk], kf, sa[c], 0, 0, 0);
                }
            }
            float corr[4];
#pragma unroll
            for (int j = 0; j < 4; j++){
                int qg = q0 + w * 16 + (lane >> 4) * 4 + j;
                float a0 = sa[0][j] * scale; if (s0 + (lane & 15) > qg)      a0 = -INFINITY;
                float a1 = sa[1][j] * scale; if (s0 + 16 + (lane & 15) > qg) a1 = -INFINITY;
                float t = fmaxf(a0, a1);
                t = fmaxf(t, __shfl_xor(t, 1));
                t = fmaxf(t, __shfl_xor(t, 2));
                t = fmaxf(t, __shfl_xor(t, 4));
                t = fmaxf(t, __shfl_xor(t, 8));
                float mn = fmaxf(mr[j], t);
                corr[j] = expf(mr[j] - mn);
                mr[j] = mn;
                float p0 = expf(a0 - mn), p1 = expf(a1 - mn);
                int rr = (lane >> 4) * 4 + j;
                u32 po0 = (u32)(rr * 64 + (lane & 15) * 2)      ^ (u32)((rr & 3) << 4);
                u32 po1 = (u32)(rr * 64 + 32 + (lane & 15) * 2) ^ (u32)((rr & 3) << 4);
                *(u16*)((char*)&Pl[w][0] + po0) = f2bf(p0);
                *(u16*)((char*)&Pl[w][0] + po1) = f2bf(p1);
                float sm = p0 + p1;
                sm += __shfl_xor(sm, 1);
                sm += __shfl_xor(sm, 2);
                sm += __shfl_xor(sm, 4);
                sm += __shfl_xor(sm, 8);
                lr[j] = lr[j] * corr[j] + sm;
            }
#pragma unroll
            for (int dt = 0; dt < 8; dt++){
                f32x4 t = accO[dt];
                t[0] *= corr[0]; t[1] *= corr[1]; t[2] *= corr[2]; t[3] *= corr[3];
                accO[dt] = t;
            }
            u32 pr = (u32)((lane & 15) * 64 + (lane >> 4) * 16) ^ (u32)(((lane & 15) & 3) << 4);
            bf16x8 pf = *(const bf16x8*)((char*)&Pl[w][0] + pr);
#pragma unroll
            for (int dt = 0; dt < 8; dt++){
                int vr = dt * 16 + (lane & 15);
                u32 vo = (u32)(vr * 64 + (lane >> 4) * 16) ^ (u32)((vr & 3) << 4);
                bf16x8 vf = *(const bf16x8*)((char*)Vt + vo);
                accO[dt] = __builtin_amdgcn_mfma_f32_16x16x32_bf16(pf, vf, accO[dt], 0, 0, 0);
            }
        }
        __syncthreads();
    }
    float inv[4];
#pragma unroll
    for (int j = 0; j < 4; j++) inv[j] = 1.0f / lr[j];
#pragma unroll
    for (int dt = 0; dt < 8; dt++)
#pragma unroll
        for (int j = 0; j < 4; j++){
            int qr = q0 + w * 16 + (lane >> 4) * 4 + j;
            int d = dt * 16 + (lane & 15);
            Y[(size_t)(b * T_ + qr) * DM + h * HD + d] = f2bf(accO[dt][j] * inv[j]);
        }
}

extern "C" void kernel_launch(void* const* d_in, const int* in_sizes, int n_in,
                              void* d_out, int out_size, void* d_ws, size_t ws_size,
                              hipStream_t stream){
    const float* x  = (const float*)d_in[0];
    const float* Wq = (const float*)d_in[1];
    const float* Wk = (const float*)d_in[2];
    const float* Wv = (const float*)d_in[3];
    const float* Wo = (const float*)d_in[4];

    char* ws = (char*)d_ws;
    size_t off = 0;
    auto alloc = [&](size_t bytes){ void* p = ws + off; off += (bytes + 255) & ~255ull; return p; };
    u16*   xb  = (u16*)alloc(4096ull * 2048 * 2);
    u16*   Wqt = (u16*)alloc(2048ull * 2048 * 2);
    u16*   Wkt = (u16*)alloc(512ull  * 2048 * 2);
    u16*   Wvt = (u16*)alloc(512ull  * 2048 * 2);
    u16*   Wot = (u16*)alloc(2048ull * 2048 * 2);
    float* qf  = (float*)alloc(4096ull * 2048 * 4);
    float* kf  = (float*)alloc(4096ull * 512  * 4);
    u16*   qbb = (u16*)alloc(4096ull * 2048 * 2);
    u16*   kbb = (u16*)alloc(4096ull * 512  * 2);
    u16*   vbb = (u16*)alloc(4096ull * 512  * 2);
    u16*   ybb = (u16*)alloc(4096ull * 2048 * 2);

    cast_v4<<<8192, 256, 0, stream>>>(x, xb);
    transW<<<dim3(64, 64), dim3(32, 8), 0, stream>>>(Wq, Wqt, 2048, 2048);
    transW<<<dim3(16, 64), dim3(32, 8), 0, stream>>>(Wk, Wkt, 2048, 512);
    transW<<<dim3(16, 64), dim3(32, 8), 0, stream>>>(Wv, Wvt, 2048, 512);
    transW<<<dim3(64, 64), dim3(32, 8), 0, stream>>>(Wo, Wot, 2048, 2048);

    gemm_bt<float><<<dim3(16, 32), 256, 0, stream>>>(xb, Wqt, qf, 4096, 2048, 2048);
    gemm_bt<float><<<dim3(4, 32),  256, 0, stream>>>(xb, Wkt, kf, 4096, 512, 2048);
    gemm_bt<u16>  <<<dim3(4, 32),  256, 0, stream>>>(xb, Wvt, vbb, 4096, 512, 2048);

    rope_cast<<<16384, 256, 0, stream>>>(qf, qbb, 4);
    rope_cast<<<4096, 256, 0, stream>>>(kf, kbb, 2);

    attn<<<dim3(32, 16, 2), 256, 0, stream>>>(qbb, kbb, vbb, ybb);

    gemm_bt<float><<<dim3(16, 32), 256, 0, stream>>>(ybb, Wot, (float*)d_out, 4096, 2048, 2048);
}

// Round 2
// 337.169 us; speedup vs baseline: 1.8636x; 1.8636x over previous
//
#include <hip/hip_runtime.h>
#include <hip/hip_bf16.h>

typedef unsigned short u16;
typedef unsigned int u32;
typedef __attribute__((ext_vector_type(4))) float f32x4;
typedef __attribute__((ext_vector_type(8))) __bf16 bf16x8;

#define B_   2
#define T_   2048
#define DM   2048
#define NH   16
#define NKV  4
#define HD   128

__device__ __forceinline__ u16 f2bf(float f){
    u32 u = __builtin_bit_cast(u32, f);
    u += 0x7FFFu + ((u >> 16) & 1u);
    return (u16)(u >> 16);
}

__device__ __forceinline__ void gld_lds16(const void* g, void* l){
    __builtin_amdgcn_global_load_lds(
        (const __attribute__((address_space(1))) void*)g,
        (__attribute__((address_space(3))) void*)l, 16, 0, 0);
}

// ---------------- elementwise cast (f32 -> bf16), vectorized ----------------
__global__ void cast_v4(const float* __restrict__ in, u16* __restrict__ out){
    int i = blockIdx.x * 256 + threadIdx.x;
    float4 v = ((const float4*)in)[i];
    ushort4 o;
    o.x = f2bf(v.x); o.y = f2bf(v.y); o.z = f2bf(v.z); o.w = f2bf(v.w);
    ((ushort4*)out)[i] = o;
}

// ---------------- W (K,N) f32 -> Wt (N,K) bf16, tiled transpose ----------------
__global__ void transW(const float* __restrict__ W, u16* __restrict__ Wt, int K, int N){
    __shared__ float tile[32][33];
    int n0 = blockIdx.x * 32, k0 = blockIdx.y * 32;
    int tx = threadIdx.x, ty = threadIdx.y;
#pragma unroll
    for (int i = 0; i < 4; i++)
        tile[ty + i * 8][tx] = W[(size_t)(k0 + ty + i * 8) * N + n0 + tx];
    __syncthreads();
#pragma unroll
    for (int i = 0; i < 4; i++)
        Wt[(size_t)(n0 + ty + i * 8) * K + k0 + tx] = f2bf(tile[tx][ty + i * 8]);
}

// ---------------- RoPE + cast, Q: plain row-major bf16 out ----------------
__global__ void rope_q(const float* __restrict__ in, u16* __restrict__ out){
    unsigned idx = blockIdx.x * 256 + threadIdx.x;
    int i = idx & 63;
    int h = (idx >> 6) & 15;
    int t = (idx >> 10) & 2047;
    int b = idx >> 21;
    size_t base = (size_t)((b << 11) | t) * 2048 + ((size_t)h << 7);
    float lo = in[base + i], hi = in[base + 64 + i];
    float ang = (float)t * exp2f((float)i * (-13.287712379549449f / 64.0f));
    float sv, cv;
    __sincosf(ang, &sv, &cv);
    out[base + i]      = f2bf(lo * cv - hi * sv);
    out[base + 64 + i] = f2bf(hi * cv + lo * sv);
}

// ---- RoPE + cast, K: tiled swizzled out [b][hkv][t32][s64][d128] (byte^=(s&7)<<4) ----
__global__ void rope_k(const float* __restrict__ in, u16* __restrict__ out){
    unsigned idx = blockIdx.x * 256 + threadIdx.x;
    int i = idx & 63;
    int h = (idx >> 6) & 3;
    int t = (idx >> 8) & 2047;
    int b = idx >> 19;
    size_t base = (size_t)((b << 11) | t) * 512 + ((size_t)h << 7);
    float lo = in[base + i], hi = in[base + 64 + i];
    float ang = (float)t * exp2f((float)i * (-13.287712379549449f / 64.0f));
    float sv, cv;
    __sincosf(ang, &sv, &cv);
    // destination: tile layout
    size_t tb = ((size_t)(b * 4 + h) * 32 + (t >> 6)) * 8192;  // u16 elems per tile
    u32 row = (u32)((t & 63) * 256);
    u32 swz = (u32)((t & 7) << 4);
    u32 b0 = row + (((u32)(2 * i)) ^ swz);
    u32 b1 = row + (((u32)(2 * i + 128)) ^ swz);
    out[tb + b0 / 2] = f2bf(lo * cv - hi * sv);
    out[tb + b1 / 2] = f2bf(hi * cv + lo * sv);
}

// ---------------- bf16 GEMM, C = A(M,K) * Bt(N,K)^T, m97 structure ----------------
// MODE 0: C = float, plain row-major
// MODE 1: V-epilogue: bf16 out, tiled transposed swizzled [b][hkv][t32][d128][s64], byte^=(d&7)<<4
template<int MODE>
__global__ __launch_bounds__(256) void gemm_bt(const u16* __restrict__ A, const u16* __restrict__ Bt,
                                               void* __restrict__ Cv, int M, int N, int K){
    __shared__ __attribute__((aligned(16))) u16 As[128 * 32];
    __shared__ __attribute__((aligned(16))) u16 Bs[128 * 32];
    const int lane = threadIdx.x & 63;
    const int w = threadIdx.x >> 6;
    const int m0 = blockIdx.y * 128, n0 = blockIdx.x * 128;
    const int wr = w >> 1, wc = w & 1;
    const f32x4 Z = {0.f, 0.f, 0.f, 0.f};
    f32x4 acc[4][4];
#pragma unroll
    for (int i = 0; i < 4; i++)
#pragma unroll
        for (int j = 0; j < 4; j++) acc[i][j] = Z;
    const int rA = (lane >> 2);
    const int cA = (lane & 3) * 8;

    for (int k0 = 0; k0 < K; k0 += 32){
#pragma unroll
        for (int i = 0; i < 2; i++){
            int s = w + i * 4;
            gld_lds16(A  + (size_t)(m0 + s * 16 + rA) * K + k0 + cA, As + s * 512);
            gld_lds16(Bt + (size_t)(n0 + s * 16 + rA) * K + k0 + cA, Bs + s * 512);
        }
        __syncthreads();
        bf16x8 af[4], bfr[4];
#pragma unroll
        for (int mi = 0; mi < 4; mi++)
            af[mi] = *(const bf16x8*)(As + (wr * 64 + mi * 16 + (lane & 15)) * 32 + (lane >> 4) * 8);
#pragma unroll
        for (int ni = 0; ni < 4; ni++)
            bfr[ni] = *(const bf16x8*)(Bs + (wc * 64 + ni * 16 + (lane & 15)) * 32 + (lane >> 4) * 8);
#pragma unroll
        for (int mi = 0; mi < 4; mi++)
#pragma unroll
            for (int ni = 0; ni < 4; ni++)
                acc[mi][ni] = __builtin_amdgcn_mfma_f32_16x16x32_bf16(af[mi], bfr[ni], acc[mi][ni], 0, 0, 0);
        __syncthreads();
    }
#pragma unroll
    for (int mi = 0; mi < 4; mi++)
#pragma unroll
        for (int ni = 0; ni < 4; ni++){
            int r0 = m0 + wr * 64 + mi * 16 + (lane >> 4) * 4;
            int c  = n0 + wc * 64 + ni * 16 + (lane & 15);
            if constexpr (MODE == 0){
                float* C = (float*)Cv;
#pragma unroll
                for (int j = 0; j < 4; j++)
                    C[(size_t)(r0 + j) * N + c] = acc[mi][ni][j];
            } else {
                // V^T tiled swizzled store
                int bb = r0 >> 11, s = r0 & 2047;
                int hk = c >> 7, d = c & 127;
                size_t base = ((size_t)(bb * 4 + hk) * 32 + (s >> 6)) * 8192;
                u32 byte = (u32)(d * 128 + ((u32)((s & 63) * 2) ^ (u32)((d & 7) << 4)));
                ushort4 o;
                o.x = f2bf(acc[mi][ni][0]); o.y = f2bf(acc[mi][ni][1]);
                o.z = f2bf(acc[mi][ni][2]); o.w = f2bf(acc[mi][ni][3]);
                *(ushort4*)((u16*)Cv + base + byte / 2) = o;
            }
        }
}

// ---------------- causal GQA flash attention, KVBLK=64, gld_lds staging ----------------
// Q: plain (b*T+t, h*128+d) bf16
// Kt: [b][hkv][t32][s64][d128] swizzled (byte^=(s&7)<<4)
// Vt: [b][hkv][t32][d128][s64] swizzled (byte^=(d&7)<<4)
__global__ __launch_bounds__(256) void attn2(const u16* __restrict__ Q, const u16* __restrict__ Kt,
                                             const u16* __restrict__ Vt, u16* __restrict__ Y){
    __shared__ __attribute__((aligned(16))) u16 Ks[64 * 128];
    __shared__ __attribute__((aligned(16))) u16 Vs[128 * 64];
    __shared__ __attribute__((aligned(16))) u16 Pl[4][16 * 64];
    const int lane = threadIdx.x & 63, w = threadIdx.x >> 6;
    const int jb = blockIdx.x, h = blockIdx.y, b = blockIdx.z;
    const int hkv = h >> 2;
    const size_t kvBase = ((size_t)(b * NKV + hkv) * 32) * 8192;  // u16 elems
    const float scale = 0.08838834764831845f;
    const f32x4 Z = {0.f, 0.f, 0.f, 0.f};

#pragma unroll 1
    for (int pass = 0; pass < 2; pass++){
        const int qt = pass == 0 ? jb : 31 - jb;
        const int q0 = qt * 64;
        const int qrow = q0 + w * 16 + (lane & 15);
        bf16x8 qfr[4];
#pragma unroll
        for (int kk = 0; kk < 4; kk++)
            qfr[kk] = *(const bf16x8*)(Q + (size_t)(b * T_ + qrow) * DM + h * HD + kk * 32 + (lane >> 4) * 8);
        f32x4 accO[8];
#pragma unroll
        for (int i = 0; i < 8; i++) accO[i] = Z;
        float mr[4] = {-INFINITY, -INFINITY, -INFINITY, -INFINITY};
        float lr[4] = {0.f, 0.f, 0.f, 0.f};
        const int nIter = qt + 1;

        for (int it = 0; it < nIter; it++){
            // ---- stage K and V tiles (16 KB each, contiguous, pre-swizzled in global) ----
            {
                const u16* kg = Kt + kvBase + (size_t)it * 8192;
                const u16* vg = Vt + kvBase + (size_t)it * 8192;
#pragma unroll
                for (int i = 0; i < 4; i++){
                    int is = w * 4 + i;
                    gld_lds16(kg + is * 512 + lane * 8, Ks + is * 512);
                    gld_lds16(vg + is * 512 + lane * 8, Vs + is * 512);
                }
            }
            __syncthreads();
            // ---- QK^T: S[16q][64s] per wave ----
            f32x4 sa[4];
#pragma unroll
            for (int c = 0; c < 4; c++) sa[c] = Z;
#pragma unroll
            for (int c = 0; c < 4; c++){
                int s = c * 16 + (lane & 15);
                u32 swz = (u32)((s & 7) << 4);
                char* kb = (char*)Ks + s * 256;
#pragma unroll
                for (int kk = 0; kk < 4; kk++){
                    bf16x8 kf = *(const bf16x8*)(kb + (((u32)(kk * 64 + (lane >> 4) * 16)) ^ swz));
                    sa[c] = __builtin_amdgcn_mfma_f32_16x16x32_bf16(qfr[kk], kf, sa[c], 0, 0, 0);
                }
            }
            // ---- softmax (wave-parallel, C-layout rows) ----
            const bool diag = (it == nIter - 1);
            float corr[4];
#pragma unroll
            for (int j = 0; j < 4; j++){
                float a0 = sa[0][j] * scale, a1 = sa[1][j] * scale;
                float a2 = sa[2][j] * scale, a3 = sa[3][j] * scale;
                if (diag){
                    int qloc = w * 16 + (lane >> 4) * 4 + j;
                    int sl = lane & 15;
                    if (sl      > qloc) a0 = -INFINITY;
                    if (sl + 16 > qloc) a1 = -INFINITY;
                    if (sl + 32 > qloc) a2 = -INFINITY;
                    if (sl + 48 > qloc) a3 = -INFINITY;
                }
                float t = fmaxf(fmaxf(a0, a1), fmaxf(a2, a3));
                t = fmaxf(t, __shfl_xor(t, 1));
                t = fmaxf(t, __shfl_xor(t, 2));
                t = fmaxf(t, __shfl_xor(t, 4));
                t = fmaxf(t, __shfl_xor(t, 8));
                float mn = fmaxf(mr[j], t);
                corr[j] = __expf(mr[j] - mn);
                mr[j] = mn;
                float p0 = __expf(a0 - mn), p1 = __expf(a1 - mn);
                float p2 = __expf(a2 - mn), p3 = __expf(a3 - mn);
                int rr = (lane >> 4) * 4 + j;
                u32 swz = (u32)((rr & 7) << 4);
                char* pb = (char*)&Pl[w][0] + rr * 128;
                u32 cb = (u32)((lane & 15) * 2);
                *(u16*)(pb + ((cb      ) ^ swz)) = f2bf(p0);
                *(u16*)(pb + ((cb + 32 ) ^ swz)) = f2bf(p1);
                *(u16*)(pb + ((cb + 64 ) ^ swz)) = f2bf(p2);
                *(u16*)(pb + ((cb + 96 ) ^ swz)) = f2bf(p3);
                float sm = p0 + p1 + p2 + p3;
                sm += __shfl_xor(sm, 1);
                sm += __shfl_xor(sm, 2);
                sm += __shfl_xor(sm, 4);
                sm += __shfl_xor(sm, 8);
                lr[j] = lr[j] * corr[j] + sm;
            }
            // ---- rescale O ----
#pragma unroll
            for (int dt = 0; dt < 8; dt++){
                f32x4 t = accO[dt];
                t[0] *= corr[0]; t[1] *= corr[1]; t[2] *= corr[2]; t[3] *= corr[3];
                accO[dt] = t;
            }
            // ---- read P as A-fragments ----
            bf16x8 pf[2];
            {
                int row = lane & 15;
                char* pb = (char*)&Pl[w][0] + row * 128;
                u32 swz = (u32)((row & 7) << 4);
                pf[0] = *(const bf16x8*)(pb + (((u32)((lane >> 4) * 16))      ^ swz));
                pf[1] = *(const bf16x8*)(pb + (((u32)((lane >> 4) * 16 + 64)) ^ swz));
            }
            // ---- PV ----
#pragma unroll
            for (int dt = 0; dt < 8; dt++){
                int d = dt * 16 + (lane & 15);
                u32 swz = (u32)((d & 7) << 4);
                char* vb = (char*)Vs + d * 128;
                bf16x8 vf0 = *(const bf16x8*)(vb + (((u32)((lane >> 4) * 16))      ^ swz));
                bf16x8 vf1 = *(const bf16x8*)(vb + (((u32)((lane >> 4) * 16 + 64)) ^ swz));
                accO[dt] = __builtin_amdgcn_mfma_f32_16x16x32_bf16(pf[0], vf0, accO[dt], 0, 0, 0);
                accO[dt] = __builtin_amdgcn_mfma_f32_16x16x32_bf16(pf[1], vf1, accO[dt], 0, 0, 0);
            }
            __syncthreads();
        }
        // ---- epilogue ----
        float inv[4];
#pragma unroll
        for (int j = 0; j < 4; j++) inv[j] = 1.0f / lr[j];
#pragma unroll
        for (int dt = 0; dt < 8; dt++)
#pragma unroll
            for (int j = 0; j < 4; j++){
                int qr = q0 + w * 16 + (lane >> 4) * 4 + j;
                int d = dt * 16 + (lane & 15);
                Y[(size_t)(b * T_ + qr) * DM + h * HD + d] = f2bf(accO[dt][j] * inv[j]);
            }
    }
}

extern "C" void kernel_launch(void* const* d_in, const int* in_sizes, int n_in,
                              void* d_out, int out_size, void* d_ws, size_t ws_size,
                              hipStream_t stream){
    const float* x  = (const float*)d_in[0];
    const float* Wq = (const float*)d_in[1];
    const float* Wk = (const float*)d_in[2];
    const float* Wv = (const float*)d_in[3];
    const float* Wo = (const float*)d_in[4];

    char* ws = (char*)d_ws;
    size_t off = 0;
    auto alloc = [&](size_t bytes){ void* p = ws + off; off += (bytes + 255) & ~255ull; return p; };
    u16*   xb  = (u16*)alloc(4096ull * 2048 * 2);
    u16*   Wqt = (u16*)alloc(2048ull * 2048 * 2);
    u16*   Wkt = (u16*)alloc(512ull  * 2048 * 2);
    u16*   Wvt = (u16*)alloc(512ull  * 2048 * 2);
    u16*   Wot = (u16*)alloc(2048ull * 2048 * 2);
    float* qf  = (float*)alloc(4096ull * 2048 * 4);
    float* kf  = (float*)alloc(4096ull * 512  * 4);
    u16*   qbb = (u16*)alloc(4096ull * 2048 * 2);
    u16*   ktl = (u16*)alloc(2ull * 4 * 32 * 8192 * 2);
    u16*   vtl = (u16*)alloc(2ull * 4 * 32 * 8192 * 2);
    u16*   ybb = (u16*)alloc(4096ull * 2048 * 2);

    cast_v4<<<8192, 256, 0, stream>>>(x, xb);
    transW<<<dim3(64, 64), dim3(32, 8), 0, stream>>>(Wq, Wqt, 2048, 2048);
    transW<<<dim3(16, 64), dim3(32, 8), 0, stream>>>(Wk, Wkt, 2048, 512);
    transW<<<dim3(16, 64), dim3(32, 8), 0, stream>>>(Wv, Wvt, 2048, 512);
    transW<<<dim3(64, 64), dim3(32, 8), 0, stream>>>(Wo, Wot, 2048, 2048);

    gemm_bt<0><<<dim3(16, 32), 256, 0, stream>>>(xb, Wqt, qf, 4096, 2048, 2048);
    gemm_bt<0><<<dim3(4, 32),  256, 0, stream>>>(xb, Wkt, kf, 4096, 512, 2048);
    gemm_bt<1><<<dim3(4, 32),  256, 0, stream>>>(xb, Wvt, vtl, 4096, 512, 2048);

    rope_q<<<16384, 256, 0, stream>>>(qf, qbb);
    rope_k<<<4096, 256, 0, stream>>>(kf, ktl);

    attn2<<<dim3(16, 16, 2), 256, 0, stream>>>(qbb, ktl, vtl, ybb);

    gemm_bt<0><<<dim3(16, 32), 256, 0, stream>>>(ybb, Wot, (float*)d_out, 4096, 2048, 2048);
}